// Round 5
// baseline (318.931 us; speedup 1.0000x reference)
//
#include <hip/hip_runtime.h>
#include <hip/hip_bf16.h>
#include <stdint.h>

#define BATCH   4096
#define IN_DIM  1024
#define OUT_DIM 1024
#define GRID_G  8
#define K8      16384            // spline K: 16 planes (8 cos + 8 sin) * 1024
#define KB      1024             // base K (silu plane)
#define NCHUNK  8                // split-K: 8 chunks (spline 16 iters + base 2 iters each)
#define WSCALE  256.0f           // spline weights scaled into e4m3 range

typedef __bf16 bf16x8 __attribute__((ext_vector_type(8)));
typedef __bf16 bf16x4 __attribute__((ext_vector_type(4)));
typedef float  f32x4  __attribute__((ext_vector_type(4)));
typedef int    i32x4  __attribute__((ext_vector_type(4)));
typedef int    i32x8  __attribute__((ext_vector_type(8)));

// ---------------------------------------------------------------------------
// prep: blocks [0,1024) = features, [1024,2048) = weight fold.
// r4->r5: non-temporal loads (x, coeff, sb, ss) and stores (A8, W8, Ab, Wb).
// Every byte this kernel touches is touched exactly once (zero reuse), so L2
// residency is pure overhead; nt keeps the streams out of the caches.
// C-zero stays cached (gemm atomics want those lines in L2). Numerically
// identical to r4.
// ---------------------------------------------------------------------------
__global__ __launch_bounds__(256) void prep(const float* __restrict__ x,
                                            const float* __restrict__ sb,
                                            const float* __restrict__ ss,
                                            const float* __restrict__ coeff,
                                            uint8_t* __restrict__ A8,
                                            uint8_t* __restrict__ W8,
                                            __bf16* __restrict__ Ab,
                                            __bf16* __restrict__ Wb,
                                            float* __restrict__ C) {
    __shared__ __align__(16) float lds[8192];        // 32 KB (w-branch only)
    const int tid = threadIdx.x;

    if (blockIdx.x < 1024) {
        // ---------------- features ----------------
        const int t  = blockIdx.x * 256 + tid;       // over B*I/16
        const int b  = t >> 6;
        const int i0 = (t & 63) * 16;

        // zero C: block covers a contiguous 16 KB region (cached: gemm atomics
        // will RMW these lines in L2)
        {
            float4 z = make_float4(0.f, 0.f, 0.f, 0.f);
            float4* cz = (float4*)(C + (size_t)blockIdx.x * 4096);
#pragma unroll
            for (int j = 0; j < 4; ++j) cz[j * 256 + tid] = z;
        }

        float xv[16];
        {
            const f32x4* xp = (const f32x4*)(x + (size_t)b * IN_DIM + i0);
            f32x4 q0 = __builtin_nontemporal_load(xp + 0);
            f32x4 q1 = __builtin_nontemporal_load(xp + 1);
            f32x4 q2 = __builtin_nontemporal_load(xp + 2);
            f32x4 q3 = __builtin_nontemporal_load(xp + 3);
#pragma unroll
            for (int j = 0; j < 4; ++j) {
                xv[j]      = q0[j];
                xv[4 + j]  = q1[j];
                xv[8 + j]  = q2[j];
                xv[12 + j] = q3[j];
            }
        }

        float c1[16], s1[16], ck[16], sk[16];
        bf16x8 va, vb;
#pragma unroll
        for (int j = 0; j < 16; ++j) {
            float e  = __expf(-xv[j]);
            float sl = xv[j] * __builtin_amdgcn_rcpf(1.f + e);
            if (j < 8) va[j & 7] = (__bf16)sl; else vb[j & 7] = (__bf16)sl;
            s1[j] = __sinf(xv[j]);
            c1[j] = __cosf(xv[j]);
            ck[j] = c1[j]; sk[j] = s1[j];
        }
        __builtin_nontemporal_store(va, (bf16x8*)(Ab + (size_t)b * IN_DIM + i0));
        __builtin_nontemporal_store(vb, (bf16x8*)(Ab + (size_t)b * IN_DIM + i0 + 8));

        uint8_t* a8 = A8 + (size_t)b * K8 + i0;
#pragma unroll
        for (int g = 0; g < GRID_G; ++g) {
            i32x4 wc, ws;
#pragma unroll
            for (int q = 0; q < 4; ++q) {
                int dc = 0, ds = 0;
                dc = __builtin_amdgcn_cvt_pk_fp8_f32(ck[4*q+0], ck[4*q+1], dc, false);
                dc = __builtin_amdgcn_cvt_pk_fp8_f32(ck[4*q+2], ck[4*q+3], dc, true);
                ds = __builtin_amdgcn_cvt_pk_fp8_f32(sk[4*q+0], sk[4*q+1], ds, false);
                ds = __builtin_amdgcn_cvt_pk_fp8_f32(sk[4*q+2], sk[4*q+3], ds, true);
                wc[q] = dc; ws[q] = ds;
            }
            __builtin_nontemporal_store(wc, (i32x4*)(a8 + (size_t)g * IN_DIM));
            __builtin_nontemporal_store(ws, (i32x4*)(a8 + (size_t)(GRID_G + g) * IN_DIM));
            if (g < GRID_G - 1) {
#pragma unroll
                for (int j = 0; j < 16; ++j) {
                    float cn = ck[j] * c1[j] - sk[j] * s1[j];
                    float sn = sk[j] * c1[j] + ck[j] * s1[j];
                    ck[j] = cn; sk[j] = sn;
                }
            }
        }
    } else {
        // ---------------- weight fold (one o-row per block) ----------------
        const int o   = blockIdx.x - 1024;
        const int i0  = tid * 4;
        const size_t oi = (size_t)o * IN_DIM + i0;

        const f32x4 s4 = __builtin_nontemporal_load((const f32x4*)(ss + oi));
        const float  s[4] = {s4[0] * WSCALE, s4[1] * WSCALE, s4[2] * WSCALE, s4[3] * WSCALE};

        {
            f32x4 b4 = __builtin_nontemporal_load((const f32x4*)(sb + oi));
            bf16x4 wv;
            wv[0] = (__bf16)b4[0]; wv[1] = (__bf16)b4[1];
            wv[2] = (__bf16)b4[2]; wv[3] = (__bf16)b4[3];
            __builtin_nontemporal_store(wv, (bf16x4*)(Wb + oi));
        }

        uint8_t* w8 = W8 + (size_t)o * K8 + i0;
        for (int p = 0; p < 2; ++p) {
            if (p) __syncthreads();                  // protect lds reuse
            const f32x4* src = (const f32x4*)(coeff + ((size_t)p * OUT_DIM + o) * (IN_DIM * GRID_G));
#pragma unroll
            for (int j = 0; j < 8; ++j) {
                f32x4 v = __builtin_nontemporal_load(src + j * 256 + tid);
                const int L   = j * 4096 + tid * 16; // linear byte offset
                const int row = L >> 7;              // 128-B row
                const int ch  = (L >> 4) & 7;        // 16-B chunk in row
                *(f32x4*)((uint8_t*)lds + row * 128 + ((ch ^ (row & 7)) << 4)) = v;
            }
            __syncthreads();
            float c[4][8];
            {
                const uint8_t* rp = (const uint8_t*)lds + tid * 128;
                const int r7 = (tid & 7) << 4;
#pragma unroll
                for (int j = 0; j < 8; ++j) {
                    f32x4 v = *(const f32x4*)(rp + ((j << 4) ^ r7));
                    c[j >> 1][(j & 1) * 4 + 0] = v[0];
                    c[j >> 1][(j & 1) * 4 + 1] = v[1];
                    c[j >> 1][(j & 1) * 4 + 2] = v[2];
                    c[j >> 1][(j & 1) * 4 + 3] = v[3];
                }
            }
#pragma unroll
            for (int g = 0; g < GRID_G; ++g) {
                int d = 0;
                d = __builtin_amdgcn_cvt_pk_fp8_f32(s[0]*c[0][g], s[1]*c[1][g], d, false);
                d = __builtin_amdgcn_cvt_pk_fp8_f32(s[2]*c[2][g], s[3]*c[3][g], d, true);
                __builtin_nontemporal_store(d, (int*)(w8 + (size_t)(p * GRID_G + g) * IN_DIM));
            }
        }
    }
}

// ---------------------------------------------------------------------------
// Unified GEMM. r4->r5: split-K deepened to 8 chunks and the kernel launched
// TWICE (kz0 = 0, 4), each with grid (8,32,4) = 1024 blocks = exactly 4
// blocks/CU. Purpose: each dispatch is ~52 µs, so prep becomes the longest
// dispatch and surfaces in the rocprof top-5 with full counters (it has been
// invisible behind the 102 µs gemm for 4 rounds). TLP per dispatch is
// UNCHANGED (4 blocks/CU); K-slices are disjoint so FETCH is unchanged; cost
// is 4 extra atomic C passes (+67 MB writes) + one launch.
// Every block: 16 spline fp8 iters (~138 cyc each) + 2 base bf16 iters
// (~155 cyc) — per-block balance preserved.
// 128x128 tile, 4 waves 2x2, 32 KB LDS, XOR 16B-chunk swizzle (c ^ (row&7))
// on staging global addr -> conflict-free b128 frag reads. XCD-aware (bm,bn)
// swizzle. Epilogue: HW f32 atomic add into zeroed C.
// ---------------------------------------------------------------------------
__global__ __launch_bounds__(256, 4) void gemm_all(const uint8_t* __restrict__ A8,
                                                   const uint8_t* __restrict__ W8,
                                                   const uint8_t* __restrict__ Ab,
                                                   const uint8_t* __restrict__ Wb,
                                                   float* __restrict__ C,
                                                   int kz0) {
    __shared__ __align__(16) uint8_t As[16384];
    __shared__ __align__(16) uint8_t Bs[16384];
    const int tid = threadIdx.x;
    const int w   = tid >> 6;
    const int l   = tid & 63;
    // XCD swizzle: flat 0..255, xcd = flat&7 (dispatch round-robin model)
    const int flat = blockIdx.y * 8 + blockIdx.x;
    const int xcd  = flat & 7;
    const int idx  = flat >> 3;                   // 0..31 within XCD
    const int bn   = (xcd & 1) * 4 + (idx & 3);   // N/128 = 8
    const int bm   = (xcd >> 1) * 8 + (idx >> 2); // M/128 = 32
    const int kz  = kz0 + blockIdx.z;             // 0..7 K-chunks
    const int wm  = w & 1;
    const int wn  = w >> 1;

    f32x4 acc[4][4] = {};

    const int srow   = l >> 3;                  // 0..7
    const int schunk = ((l & 7) ^ srow) * 16;   // byte offset of swizzled 16B chunk
    const int lm = l & 15;
    const int q  = l >> 4;                      // 0..3

    // ---------------- spline fp8 phase (chunk kz: 16 iters) ----------------
    {
        const uint8_t* Ag = A8 + (size_t)(bm * 128 + w * 32 + srow) * K8 + kz * (K8 / NCHUNK) + schunk;
        const uint8_t* Bg = W8 + (size_t)(bn * 128 + w * 32 + srow) * K8 + kz * (K8 / NCHUNK) + schunk;
        const int c0 = (q * 2) << 4, c1 = (q * 2 + 1) << 4;   // lane's two chunk offsets

        for (int ks = 0; ks < (K8 / NCHUNK) / 128; ++ks) {
#pragma unroll
            for (int j = 0; j < 4; ++j) {
                __builtin_amdgcn_global_load_lds(
                    (const uint32_t*)(Ag + (size_t)(j * 8) * K8),
                    (uint32_t*)(As + (w * 32 + j * 8) * 128), 16, 0, 0);
                __builtin_amdgcn_global_load_lds(
                    (const uint32_t*)(Bg + (size_t)(j * 8) * K8),
                    (uint32_t*)(Bs + (w * 32 + j * 8) * 128), 16, 0, 0);
            }
            Ag += 128; Bg += 128;
            __syncthreads();

            i32x8 bf[4];
#pragma unroll
            for (int j = 0; j < 4; ++j) {
                const int row = wn * 64 + j * 16 + lm;
                const int sw  = (row & 7) << 4;
                const uint8_t* rp = Bs + row * 128;
                i32x4 lo = *(const i32x4*)(rp + (c0 ^ sw));
                i32x4 hi = *(const i32x4*)(rp + (c1 ^ sw));
                bf[j] = __builtin_shufflevector(lo, hi, 0, 1, 2, 3, 4, 5, 6, 7);
            }
#pragma unroll
            for (int i = 0; i < 4; ++i) {
                const int row = wm * 64 + i * 16 + lm;
                const int sw  = (row & 7) << 4;
                const uint8_t* rp = As + row * 128;
                i32x4 lo = *(const i32x4*)(rp + (c0 ^ sw));
                i32x4 hi = *(const i32x4*)(rp + (c1 ^ sw));
                i32x8 af = __builtin_shufflevector(lo, hi, 0, 1, 2, 3, 4, 5, 6, 7);
#pragma unroll
                for (int j = 0; j < 4; ++j)
                    acc[i][j] = __builtin_amdgcn_mfma_scale_f32_16x16x128_f8f6f4(
                        af, bf[j], acc[i][j], 0, 0, 0, 0x7f7f7f7f, 0, 0x7f7f7f7f);
            }
            __syncthreads();
        }
    }

    // undo the WSCALE applied to the fp8 spline weights (in-register)
#pragma unroll
    for (int i = 0; i < 4; ++i)
#pragma unroll
        for (int j = 0; j < 4; ++j)
            acc[i][j] *= (1.0f / WSCALE);

    // ---------------- base bf16 phase: K-slice kz (128 elems, 2 iters) -----
    {
        const uint8_t* Ag = Ab + (size_t)(bm * 128 + w * 32 + srow) * (KB * 2) + kz * 256 + schunk;
        const uint8_t* Bg = Wb + (size_t)(bn * 128 + w * 32 + srow) * (KB * 2) + kz * 256 + schunk;

        for (int ks = 0; ks < 2; ++ks) {
#pragma unroll
            for (int j = 0; j < 4; ++j) {
                __builtin_amdgcn_global_load_lds(
                    (const uint32_t*)(Ag + (size_t)(j * 8) * (KB * 2)),
                    (uint32_t*)(As + (w * 32 + j * 8) * 128), 16, 0, 0);
                __builtin_amdgcn_global_load_lds(
                    (const uint32_t*)(Bg + (size_t)(j * 8) * (KB * 2)),
                    (uint32_t*)(Bs + (w * 32 + j * 8) * 128), 16, 0, 0);
            }
            Ag += 128; Bg += 128;
            __syncthreads();

#pragma unroll
            for (int h = 0; h < 2; ++h) {
                bf16x8 af[4], bfr[4];
#pragma unroll
                for (int i = 0; i < 4; ++i) {
                    const int row = wm * 64 + i * 16 + lm;
                    af[i] = *(const bf16x8*)(As + row * 128 + ((((h * 4 + q) ^ (row & 7))) << 4));
                }
#pragma unroll
                for (int j = 0; j < 4; ++j) {
                    const int row = wn * 64 + j * 16 + lm;
                    bfr[j] = *(const bf16x8*)(Bs + row * 128 + ((((h * 4 + q) ^ (row & 7))) << 4));
                }
#pragma unroll
                for (int i = 0; i < 4; ++i)
#pragma unroll
                    for (int j = 0; j < 4; ++j)
                        acc[i][j] = __builtin_amdgcn_mfma_f32_16x16x32_bf16(af[i], bfr[j], acc[i][j], 0, 0, 0);
            }
            __syncthreads();
        }
    }

    // epilogue: C/D layout col = lane&15, row = (lane>>4)*4 + reg
    const int row0 = bm * 128 + wm * 64 + q * 4;
    const int col0 = bn * 128 + wn * 64 + lm;
#pragma unroll
    for (int i = 0; i < 4; ++i)
#pragma unroll
        for (int j = 0; j < 4; ++j)
#pragma unroll
            for (int r = 0; r < 4; ++r)
                unsafeAtomicAdd(&C[(size_t)(row0 + i * 16 + r) * OUT_DIM + col0 + j * 16],
                                acc[i][j][r]);
}

// ---------------------------------------------------------------------------
extern "C" void kernel_launch(void* const* d_in, const int* in_sizes, int n_in,
                              void* d_out, int out_size, void* d_ws, size_t ws_size,
                              hipStream_t stream) {
    const float* x     = (const float*)d_in[0];   // (B, I)
    const float* sb    = (const float*)d_in[1];   // (O, I)
    const float* ss    = (const float*)d_in[2];   // (O, I)
    const float* coeff = (const float*)d_in[3];   // (2, O, I, G)
    float* out = (float*)d_out;                   // (B, O)

    uint8_t* A8 = (uint8_t*)d_ws;                          // 4096*16384 fp8 = 67.1 MB
    uint8_t* W8 = A8 + (size_t)BATCH * K8;                 // 1024*16384 fp8 = 16.8 MB
    __bf16*  Ab = (__bf16*)(W8 + (size_t)OUT_DIM * K8);    // 4096*1024 bf16 = 8.4 MB
    __bf16*  Wb = Ab + (size_t)BATCH * KB;                 // 1024*1024 bf16 = 2.1 MB

    hipLaunchKernelGGL(prep, dim3(2048), dim3(256), 0, stream,
                       x, sb, ss, coeff, A8, W8, Ab, Wb, out);
    hipLaunchKernelGGL(gemm_all, dim3(OUT_DIM / 128, BATCH / 128, NCHUNK / 2), dim3(256), 0, stream,
                       A8, W8, (const uint8_t*)Ab, (const uint8_t*)Wb, out, 0);
    hipLaunchKernelGGL(gemm_all, dim3(OUT_DIM / 128, BATCH / 128, NCHUNK / 2), dim3(256), 0, stream,
                       A8, W8, (const uint8_t*)Ab, (const uint8_t*)Wb, out, 4);
}

// Round 6
// 263.310 us; speedup vs baseline: 1.2112x; 1.2112x over previous
//
#include <hip/hip_runtime.h>
#include <hip/hip_bf16.h>
#include <stdint.h>

#define BATCH   4096
#define IN_DIM  1024
#define OUT_DIM 1024
#define GRID_G  8
#define K8      16384            // spline K: 16 planes (8 cos + 8 sin) * 1024
#define KB      1024             // base K (silu plane)
#define SPLITK  2                // split-K: 2 chunks (spline 64 iters + base 8 iters each)
#define WSCALE  256.0f           // spline weights scaled into e4m3 range

typedef __bf16 bf16x8 __attribute__((ext_vector_type(8)));
typedef __bf16 bf16x4 __attribute__((ext_vector_type(4)));
typedef float  f32x4  __attribute__((ext_vector_type(4)));
typedef int    i32x4  __attribute__((ext_vector_type(4)));
typedef int    i32x8  __attribute__((ext_vector_type(8)));

// ---------------------------------------------------------------------------
// prep: blocks [0,1024) = features, [1024,2048) = weight fold. (unchanged r5)
// nt loads/stores on all once-touched streams (kept: residual 133->122 in r5).
// ---------------------------------------------------------------------------
__global__ __launch_bounds__(256) void prep(const float* __restrict__ x,
                                            const float* __restrict__ sb,
                                            const float* __restrict__ ss,
                                            const float* __restrict__ coeff,
                                            uint8_t* __restrict__ A8,
                                            uint8_t* __restrict__ W8,
                                            __bf16* __restrict__ Ab,
                                            __bf16* __restrict__ Wb,
                                            float* __restrict__ C) {
    __shared__ __align__(16) float lds[8192];        // 32 KB (w-branch only)
    const int tid = threadIdx.x;

    if (blockIdx.x < 1024) {
        // ---------------- features ----------------
        const int t  = blockIdx.x * 256 + tid;       // over B*I/16
        const int b  = t >> 6;
        const int i0 = (t & 63) * 16;

        {
            float4 z = make_float4(0.f, 0.f, 0.f, 0.f);
            float4* cz = (float4*)(C + (size_t)blockIdx.x * 4096);
#pragma unroll
            for (int j = 0; j < 4; ++j) cz[j * 256 + tid] = z;
        }

        float xv[16];
        {
            const f32x4* xp = (const f32x4*)(x + (size_t)b * IN_DIM + i0);
            f32x4 q0 = __builtin_nontemporal_load(xp + 0);
            f32x4 q1 = __builtin_nontemporal_load(xp + 1);
            f32x4 q2 = __builtin_nontemporal_load(xp + 2);
            f32x4 q3 = __builtin_nontemporal_load(xp + 3);
#pragma unroll
            for (int j = 0; j < 4; ++j) {
                xv[j]      = q0[j];
                xv[4 + j]  = q1[j];
                xv[8 + j]  = q2[j];
                xv[12 + j] = q3[j];
            }
        }

        float c1[16], s1[16], ck[16], sk[16];
        bf16x8 va, vb;
#pragma unroll
        for (int j = 0; j < 16; ++j) {
            float e  = __expf(-xv[j]);
            float sl = xv[j] * __builtin_amdgcn_rcpf(1.f + e);
            if (j < 8) va[j & 7] = (__bf16)sl; else vb[j & 7] = (__bf16)sl;
            s1[j] = __sinf(xv[j]);
            c1[j] = __cosf(xv[j]);
            ck[j] = c1[j]; sk[j] = s1[j];
        }
        __builtin_nontemporal_store(va, (bf16x8*)(Ab + (size_t)b * IN_DIM + i0));
        __builtin_nontemporal_store(vb, (bf16x8*)(Ab + (size_t)b * IN_DIM + i0 + 8));

        uint8_t* a8 = A8 + (size_t)b * K8 + i0;
#pragma unroll
        for (int g = 0; g < GRID_G; ++g) {
            i32x4 wc, ws;
#pragma unroll
            for (int q = 0; q < 4; ++q) {
                int dc = 0, ds = 0;
                dc = __builtin_amdgcn_cvt_pk_fp8_f32(ck[4*q+0], ck[4*q+1], dc, false);
                dc = __builtin_amdgcn_cvt_pk_fp8_f32(ck[4*q+2], ck[4*q+3], dc, true);
                ds = __builtin_amdgcn_cvt_pk_fp8_f32(sk[4*q+0], sk[4*q+1], ds, false);
                ds = __builtin_amdgcn_cvt_pk_fp8_f32(sk[4*q+2], sk[4*q+3], ds, true);
                wc[q] = dc; ws[q] = ds;
            }
            __builtin_nontemporal_store(wc, (i32x4*)(a8 + (size_t)g * IN_DIM));
            __builtin_nontemporal_store(ws, (i32x4*)(a8 + (size_t)(GRID_G + g) * IN_DIM));
            if (g < GRID_G - 1) {
#pragma unroll
                for (int j = 0; j < 16; ++j) {
                    float cn = ck[j] * c1[j] - sk[j] * s1[j];
                    float sn = sk[j] * c1[j] + ck[j] * s1[j];
                    ck[j] = cn; sk[j] = sn;
                }
            }
        }
    } else {
        // ---------------- weight fold (one o-row per block) ----------------
        const int o   = blockIdx.x - 1024;
        const int i0  = tid * 4;
        const size_t oi = (size_t)o * IN_DIM + i0;

        const f32x4 s4 = __builtin_nontemporal_load((const f32x4*)(ss + oi));
        const float  s[4] = {s4[0] * WSCALE, s4[1] * WSCALE, s4[2] * WSCALE, s4[3] * WSCALE};

        {
            f32x4 b4 = __builtin_nontemporal_load((const f32x4*)(sb + oi));
            bf16x4 wv;
            wv[0] = (__bf16)b4[0]; wv[1] = (__bf16)b4[1];
            wv[2] = (__bf16)b4[2]; wv[3] = (__bf16)b4[3];
            __builtin_nontemporal_store(wv, (bf16x4*)(Wb + oi));
        }

        uint8_t* w8 = W8 + (size_t)o * K8 + i0;
        for (int p = 0; p < 2; ++p) {
            if (p) __syncthreads();                  // protect lds reuse
            const f32x4* src = (const f32x4*)(coeff + ((size_t)p * OUT_DIM + o) * (IN_DIM * GRID_G));
#pragma unroll
            for (int j = 0; j < 8; ++j) {
                f32x4 v = __builtin_nontemporal_load(src + j * 256 + tid);
                const int L   = j * 4096 + tid * 16; // linear byte offset
                const int row = L >> 7;              // 128-B row
                const int ch  = (L >> 4) & 7;        // 16-B chunk in row
                *(f32x4*)((uint8_t*)lds + row * 128 + ((ch ^ (row & 7)) << 4)) = v;
            }
            __syncthreads();
            float c[4][8];
            {
                const uint8_t* rp = (const uint8_t*)lds + tid * 128;
                const int r7 = (tid & 7) << 4;
#pragma unroll
                for (int j = 0; j < 8; ++j) {
                    f32x4 v = *(const f32x4*)(rp + ((j << 4) ^ r7));
                    c[j >> 1][(j & 1) * 4 + 0] = v[0];
                    c[j >> 1][(j & 1) * 4 + 1] = v[1];
                    c[j >> 1][(j & 1) * 4 + 2] = v[2];
                    c[j >> 1][(j & 1) * 4 + 3] = v[3];
                }
            }
#pragma unroll
            for (int g = 0; g < GRID_G; ++g) {
                int d = 0;
                d = __builtin_amdgcn_cvt_pk_fp8_f32(s[0]*c[0][g], s[1]*c[1][g], d, false);
                d = __builtin_amdgcn_cvt_pk_fp8_f32(s[2]*c[2][g], s[3]*c[3][g], d, true);
                __builtin_nontemporal_store(d, (int*)(w8 + (size_t)(p * GRID_G + g) * IN_DIM));
            }
        }
    }
}

// ---------------------------------------------------------------------------
// Unified GEMM, r5->r6: the 5-round measurement series established
// dur = HBM_bytes / ~1.9 TB/s regardless of compute (halving work left time
// unchanged, MfmaUtil halved). Root cause: every 8 KB stage is followed by a
// full vmcnt(0) drain at __syncthreads -> ~30% issue duty cycle.
// Changes:
//  1. bytes: single dispatch, SPLITK 4->2 (C atomic passes 4->2: WRITE 67->34
//     MB; C-RMW refetch halves). Grid (8,32,2) = 512 blocks = exactly 2/CU.
//  2. BW: true LDS double-buffer (2 x 32 KB, launch_bounds(256,2)). K-loop
//     manually unrolled x2 so buffer indices are COMPILE-TIME constants
//     (As[0]/As[1] ranges provably disjoint -> compiler need not serialize
//     the in-flight stage against the current buffer's ds_reads). Per K-step:
//     issue next tile's 8 global_load_lds, then frag-read + MFMA current,
//     then ONE __syncthreads (its vmcnt(0) retires loads that had the whole
//     compute phase to fly).
// Per block: 64 spline iters + 8 base iters, all blocks identical (balanced).
// XCD swizzle unchanged (kz planes share xcd -> atomic L2 locality).
// ---------------------------------------------------------------------------
__global__ __launch_bounds__(256, 2) void gemm_all(const uint8_t* __restrict__ A8,
                                                   const uint8_t* __restrict__ W8,
                                                   const uint8_t* __restrict__ Ab,
                                                   const uint8_t* __restrict__ Wb,
                                                   float* __restrict__ C) {
    __shared__ __align__(16) uint8_t As[2][16384];
    __shared__ __align__(16) uint8_t Bs[2][16384];
    const int tid = threadIdx.x;
    const int w   = tid >> 6;
    const int l   = tid & 63;
    // XCD swizzle: flat 0..255, xcd = flat&7 (dispatch round-robin model)
    const int flat = blockIdx.y * 8 + blockIdx.x;
    const int xcd  = flat & 7;
    const int idx  = flat >> 3;                   // 0..31 within XCD
    const int bn   = (xcd & 1) * 4 + (idx & 3);   // N/128 = 8
    const int bm   = (xcd >> 1) * 8 + (idx >> 2); // M/128 = 32
    const int kz  = blockIdx.z;                   // 0..1 K-chunks
    const int wm  = w & 1;
    const int wn  = w >> 1;

    f32x4 acc[4][4] = {};

    const int srow   = l >> 3;                  // 0..7
    const int schunk = ((l & 7) ^ srow) * 16;   // byte offset of swizzled 16B chunk
    const int lm = l & 15;
    const int q  = l >> 4;                      // 0..3
    const int c0 = (q * 2) << 4, c1 = (q * 2 + 1) << 4;

    // ---------------- spline fp8 phase (chunk kz: 64 iters, dbuf) ----------
    {
        const uint8_t* Ag = A8 + (size_t)(bm * 128 + w * 32 + srow) * K8 + kz * (K8 / SPLITK) + schunk;
        const uint8_t* Bg = W8 + (size_t)(bn * 128 + w * 32 + srow) * K8 + kz * (K8 / SPLITK) + schunk;

        auto stage = [&](int bb) {
#pragma unroll
            for (int j = 0; j < 4; ++j) {
                __builtin_amdgcn_global_load_lds(
                    (const uint32_t*)(Ag + (size_t)(j * 8) * K8),
                    (uint32_t*)(&As[bb][(w * 32 + j * 8) * 128]), 16, 0, 0);
                __builtin_amdgcn_global_load_lds(
                    (const uint32_t*)(Bg + (size_t)(j * 8) * K8),
                    (uint32_t*)(&Bs[bb][(w * 32 + j * 8) * 128]), 16, 0, 0);
            }
            Ag += 128; Bg += 128;
        };
        auto compute = [&](int bb) {
            i32x8 bf[4];
#pragma unroll
            for (int j = 0; j < 4; ++j) {
                const int row = wn * 64 + j * 16 + lm;
                const int sw  = (row & 7) << 4;
                const uint8_t* rp = &Bs[bb][row * 128];
                i32x4 lo = *(const i32x4*)(rp + (c0 ^ sw));
                i32x4 hi = *(const i32x4*)(rp + (c1 ^ sw));
                bf[j] = __builtin_shufflevector(lo, hi, 0, 1, 2, 3, 4, 5, 6, 7);
            }
#pragma unroll
            for (int i = 0; i < 4; ++i) {
                const int row = wm * 64 + i * 16 + lm;
                const int sw  = (row & 7) << 4;
                const uint8_t* rp = &As[bb][row * 128];
                i32x4 lo = *(const i32x4*)(rp + (c0 ^ sw));
                i32x4 hi = *(const i32x4*)(rp + (c1 ^ sw));
                i32x8 af = __builtin_shufflevector(lo, hi, 0, 1, 2, 3, 4, 5, 6, 7);
#pragma unroll
                for (int j = 0; j < 4; ++j)
                    acc[i][j] = __builtin_amdgcn_mfma_scale_f32_16x16x128_f8f6f4(
                        af, bf[j], acc[i][j], 0, 0, 0, 0x7f7f7f7f, 0, 0x7f7f7f7f);
            }
        };

        stage(0);                 // tile 0
        __syncthreads();
        for (int ks = 0; ks < 32; ++ks) {           // 64 tiles = 32 pairs
            stage(1);                               // tile 2ks+1 in flight
            compute(0);                             // tile 2ks
            __syncthreads();
            if (ks < 31) stage(0);                  // tile 2ks+2 in flight
            compute(1);                             // tile 2ks+1
            __syncthreads();
        }
    }

    // undo the WSCALE applied to the fp8 spline weights (in-register)
#pragma unroll
    for (int i = 0; i < 4; ++i)
#pragma unroll
        for (int j = 0; j < 4; ++j)
            acc[i][j] *= (1.0f / WSCALE);

    // ---------------- base bf16 phase: K-slice kz (512 elems, 8 iters) -----
    {
        const uint8_t* Ag = Ab + (size_t)(bm * 128 + w * 32 + srow) * (KB * 2) + kz * (KB * 2 / SPLITK) + schunk;
        const uint8_t* Bg = Wb + (size_t)(bn * 128 + w * 32 + srow) * (KB * 2) + kz * (KB * 2 / SPLITK) + schunk;

        auto stage = [&](int bb) {
#pragma unroll
            for (int j = 0; j < 4; ++j) {
                __builtin_amdgcn_global_load_lds(
                    (const uint32_t*)(Ag + (size_t)(j * 8) * (KB * 2)),
                    (uint32_t*)(&As[bb][(w * 32 + j * 8) * 128]), 16, 0, 0);
                __builtin_amdgcn_global_load_lds(
                    (const uint32_t*)(Bg + (size_t)(j * 8) * (KB * 2)),
                    (uint32_t*)(&Bs[bb][(w * 32 + j * 8) * 128]), 16, 0, 0);
            }
            Ag += 128; Bg += 128;
        };
        auto compute = [&](int bb) {
#pragma unroll
            for (int h = 0; h < 2; ++h) {
                bf16x8 af[4], bfr[4];
#pragma unroll
                for (int i = 0; i < 4; ++i) {
                    const int row = wm * 64 + i * 16 + lm;
                    af[i] = *(const bf16x8*)(&As[bb][row * 128 + ((((h * 4 + q) ^ (row & 7))) << 4)]);
                }
#pragma unroll
                for (int j = 0; j < 4; ++j) {
                    const int row = wn * 64 + j * 16 + lm;
                    bfr[j] = *(const bf16x8*)(&Bs[bb][row * 128 + ((((h * 4 + q) ^ (row & 7))) << 4)]);
                }
#pragma unroll
                for (int i = 0; i < 4; ++i)
#pragma unroll
                    for (int j = 0; j < 4; ++j)
                        acc[i][j] = __builtin_amdgcn_mfma_f32_16x16x32_bf16(af[i], bfr[j], acc[i][j], 0, 0, 0);
            }
        };

        stage(0);
        __syncthreads();
        for (int kb = 0; kb < 4; ++kb) {            // 8 tiles = 4 pairs
            stage(1);
            compute(0);
            __syncthreads();
            if (kb < 3) stage(0);
            compute(1);
            __syncthreads();
        }
    }

    // epilogue: C/D layout col = lane&15, row = (lane>>4)*4 + reg
    const int row0 = bm * 128 + wm * 64 + q * 4;
    const int col0 = bn * 128 + wn * 64 + lm;
#pragma unroll
    for (int i = 0; i < 4; ++i)
#pragma unroll
        for (int j = 0; j < 4; ++j)
#pragma unroll
            for (int r = 0; r < 4; ++r)
                unsafeAtomicAdd(&C[(size_t)(row0 + i * 16 + r) * OUT_DIM + col0 + j * 16],
                                acc[i][j][r]);
}

// ---------------------------------------------------------------------------
extern "C" void kernel_launch(void* const* d_in, const int* in_sizes, int n_in,
                              void* d_out, int out_size, void* d_ws, size_t ws_size,
                              hipStream_t stream) {
    const float* x     = (const float*)d_in[0];   // (B, I)
    const float* sb    = (const float*)d_in[1];   // (O, I)
    const float* ss    = (const float*)d_in[2];   // (O, I)
    const float* coeff = (const float*)d_in[3];   // (2, O, I, G)
    float* out = (float*)d_out;                   // (B, O)

    uint8_t* A8 = (uint8_t*)d_ws;                          // 4096*16384 fp8 = 67.1 MB
    uint8_t* W8 = A8 + (size_t)BATCH * K8;                 // 1024*16384 fp8 = 16.8 MB
    __bf16*  Ab = (__bf16*)(W8 + (size_t)OUT_DIM * K8);    // 4096*1024 bf16 = 8.4 MB
    __bf16*  Wb = Ab + (size_t)BATCH * KB;                 // 1024*1024 bf16 = 2.1 MB

    hipLaunchKernelGGL(prep, dim3(2048), dim3(256), 0, stream,
                       x, sb, ss, coeff, A8, W8, Ab, Wb, out);
    hipLaunchKernelGGL(gemm_all, dim3(OUT_DIM / 128, BATCH / 128, SPLITK), dim3(256), 0, stream,
                       A8, W8, (const uint8_t*)Ab, (const uint8_t*)Wb, out);
}

// Round 7
// 243.196 us; speedup vs baseline: 1.3114x; 1.0827x over previous
//
#include <hip/hip_runtime.h>
#include <hip/hip_bf16.h>
#include <stdint.h>

#define BATCH   4096
#define IN_DIM  1024
#define OUT_DIM 1024
#define GRID_G  8
#define K8      16384            // spline K: 16 planes (8 cos + 8 sin) * 1024
#define KB      1024             // base K (silu plane)
#define SPLITK  2                // split-K: 2 chunks (spline 64 iters + base 8 iters each)
#define WSCALE  256.0f           // spline weights scaled into e4m3 range

typedef __bf16 bf16x8 __attribute__((ext_vector_type(8)));
typedef __bf16 bf16x4 __attribute__((ext_vector_type(4)));
typedef float  f32x4  __attribute__((ext_vector_type(4)));
typedef int    i32x4  __attribute__((ext_vector_type(4)));
typedef int    i32x8  __attribute__((ext_vector_type(8)));

// ---------------------------------------------------------------------------
// prep: blocks [0,1024) = features, [1024,2048) = weight fold. (unchanged r5)
// nt loads/stores on all once-touched streams (kept: residual 133->122 in r5).
// ---------------------------------------------------------------------------
__global__ __launch_bounds__(256) void prep(const float* __restrict__ x,
                                            const float* __restrict__ sb,
                                            const float* __restrict__ ss,
                                            const float* __restrict__ coeff,
                                            uint8_t* __restrict__ A8,
                                            uint8_t* __restrict__ W8,
                                            __bf16* __restrict__ Ab,
                                            __bf16* __restrict__ Wb,
                                            float* __restrict__ C) {
    __shared__ __align__(16) float lds[8192];        // 32 KB (w-branch only)
    const int tid = threadIdx.x;

    if (blockIdx.x < 1024) {
        // ---------------- features ----------------
        const int t  = blockIdx.x * 256 + tid;       // over B*I/16
        const int b  = t >> 6;
        const int i0 = (t & 63) * 16;

        {
            float4 z = make_float4(0.f, 0.f, 0.f, 0.f);
            float4* cz = (float4*)(C + (size_t)blockIdx.x * 4096);
#pragma unroll
            for (int j = 0; j < 4; ++j) cz[j * 256 + tid] = z;
        }

        float xv[16];
        {
            const f32x4* xp = (const f32x4*)(x + (size_t)b * IN_DIM + i0);
            f32x4 q0 = __builtin_nontemporal_load(xp + 0);
            f32x4 q1 = __builtin_nontemporal_load(xp + 1);
            f32x4 q2 = __builtin_nontemporal_load(xp + 2);
            f32x4 q3 = __builtin_nontemporal_load(xp + 3);
#pragma unroll
            for (int j = 0; j < 4; ++j) {
                xv[j]      = q0[j];
                xv[4 + j]  = q1[j];
                xv[8 + j]  = q2[j];
                xv[12 + j] = q3[j];
            }
        }

        float c1[16], s1[16], ck[16], sk[16];
        bf16x8 va, vb;
#pragma unroll
        for (int j = 0; j < 16; ++j) {
            float e  = __expf(-xv[j]);
            float sl = xv[j] * __builtin_amdgcn_rcpf(1.f + e);
            if (j < 8) va[j & 7] = (__bf16)sl; else vb[j & 7] = (__bf16)sl;
            s1[j] = __sinf(xv[j]);
            c1[j] = __cosf(xv[j]);
            ck[j] = c1[j]; sk[j] = s1[j];
        }
        __builtin_nontemporal_store(va, (bf16x8*)(Ab + (size_t)b * IN_DIM + i0));
        __builtin_nontemporal_store(vb, (bf16x8*)(Ab + (size_t)b * IN_DIM + i0 + 8));

        uint8_t* a8 = A8 + (size_t)b * K8 + i0;
#pragma unroll
        for (int g = 0; g < GRID_G; ++g) {
            i32x4 wc, ws;
#pragma unroll
            for (int q = 0; q < 4; ++q) {
                int dc = 0, ds = 0;
                dc = __builtin_amdgcn_cvt_pk_fp8_f32(ck[4*q+0], ck[4*q+1], dc, false);
                dc = __builtin_amdgcn_cvt_pk_fp8_f32(ck[4*q+2], ck[4*q+3], dc, true);
                ds = __builtin_amdgcn_cvt_pk_fp8_f32(sk[4*q+0], sk[4*q+1], ds, false);
                ds = __builtin_amdgcn_cvt_pk_fp8_f32(sk[4*q+2], sk[4*q+3], ds, true);
                wc[q] = dc; ws[q] = ds;
            }
            __builtin_nontemporal_store(wc, (i32x4*)(a8 + (size_t)g * IN_DIM));
            __builtin_nontemporal_store(ws, (i32x4*)(a8 + (size_t)(GRID_G + g) * IN_DIM));
            if (g < GRID_G - 1) {
#pragma unroll
                for (int j = 0; j < 16; ++j) {
                    float cn = ck[j] * c1[j] - sk[j] * s1[j];
                    float sn = sk[j] * c1[j] + ck[j] * s1[j];
                    ck[j] = cn; sk[j] = sn;
                }
            }
        }
    } else {
        // ---------------- weight fold (one o-row per block) ----------------
        const int o   = blockIdx.x - 1024;
        const int i0  = tid * 4;
        const size_t oi = (size_t)o * IN_DIM + i0;

        const f32x4 s4 = __builtin_nontemporal_load((const f32x4*)(ss + oi));
        const float  s[4] = {s4[0] * WSCALE, s4[1] * WSCALE, s4[2] * WSCALE, s4[3] * WSCALE};

        {
            f32x4 b4 = __builtin_nontemporal_load((const f32x4*)(sb + oi));
            bf16x4 wv;
            wv[0] = (__bf16)b4[0]; wv[1] = (__bf16)b4[1];
            wv[2] = (__bf16)b4[2]; wv[3] = (__bf16)b4[3];
            __builtin_nontemporal_store(wv, (bf16x4*)(Wb + oi));
        }

        uint8_t* w8 = W8 + (size_t)o * K8 + i0;
        for (int p = 0; p < 2; ++p) {
            if (p) __syncthreads();                  // protect lds reuse
            const f32x4* src = (const f32x4*)(coeff + ((size_t)p * OUT_DIM + o) * (IN_DIM * GRID_G));
#pragma unroll
            for (int j = 0; j < 8; ++j) {
                f32x4 v = __builtin_nontemporal_load(src + j * 256 + tid);
                const int L   = j * 4096 + tid * 16; // linear byte offset
                const int row = L >> 7;              // 128-B row
                const int ch  = (L >> 4) & 7;        // 16-B chunk in row
                *(f32x4*)((uint8_t*)lds + row * 128 + ((ch ^ (row & 7)) << 4)) = v;
            }
            __syncthreads();
            float c[4][8];
            {
                const uint8_t* rp = (const uint8_t*)lds + tid * 128;
                const int r7 = (tid & 7) << 4;
#pragma unroll
                for (int j = 0; j < 8; ++j) {
                    f32x4 v = *(const f32x4*)(rp + ((j << 4) ^ r7));
                    c[j >> 1][(j & 1) * 4 + 0] = v[0];
                    c[j >> 1][(j & 1) * 4 + 1] = v[1];
                    c[j >> 1][(j & 1) * 4 + 2] = v[2];
                    c[j >> 1][(j & 1) * 4 + 3] = v[3];
                }
            }
#pragma unroll
            for (int g = 0; g < GRID_G; ++g) {
                int d = 0;
                d = __builtin_amdgcn_cvt_pk_fp8_f32(s[0]*c[0][g], s[1]*c[1][g], d, false);
                d = __builtin_amdgcn_cvt_pk_fp8_f32(s[2]*c[2][g], s[3]*c[3][g], d, true);
                __builtin_nontemporal_store(d, (int*)(w8 + (size_t)(p * GRID_G + g) * IN_DIM));
            }
        }
    }
}

// ---------------------------------------------------------------------------
// Unified GEMM, r6->r7: keep r6's double-buffer + byte savings (147 MB), but
// replace __syncthreads (which drains vmcnt(0) -> kills the pipeline, the
// r6 regression) with RAW s_barrier + COUNTED s_waitcnt vmcnt(8): only the
// current buffer's 8 staging loads are waited; the next buffer's 8 stay in
// flight ACROSS the barrier (T4, m218: counted-vs-drain = +38-73%).
// Safety (m218 pattern): each wave waits its own vmcnt(8) -> s_barrier ->
// every wave's slice landed. Re-stage of buf[t&1] is issued only after the
// barrier following compute(t): all reads retired (each MFMA's issue forces
// the lgkmcnt wait on its ds_reads, and all MFMAs precede the barrier in
// program order). Tail peels to vmcnt(0). sched_barrier(0) after waitcnt
// (rule #18). Grid (8,32,2) = 512 blocks = exactly 2/CU, 64 KB LDS.
// ---------------------------------------------------------------------------
__global__ __launch_bounds__(256, 2) void gemm_all(const uint8_t* __restrict__ A8,
                                                   const uint8_t* __restrict__ W8,
                                                   const uint8_t* __restrict__ Ab,
                                                   const uint8_t* __restrict__ Wb,
                                                   float* __restrict__ C) {
    __shared__ __align__(16) uint8_t As[2][16384];
    __shared__ __align__(16) uint8_t Bs[2][16384];
    const int tid = threadIdx.x;
    const int w   = tid >> 6;
    const int l   = tid & 63;
    // XCD swizzle: flat 0..255, xcd = flat&7 (dispatch round-robin model)
    const int flat = blockIdx.y * 8 + blockIdx.x;
    const int xcd  = flat & 7;
    const int idx  = flat >> 3;                   // 0..31 within XCD
    const int bn   = (xcd & 1) * 4 + (idx & 3);   // N/128 = 8
    const int bm   = (xcd >> 1) * 8 + (idx >> 2); // M/128 = 32
    const int kz  = blockIdx.z;                   // 0..1 K-chunks
    const int wm  = w & 1;
    const int wn  = w >> 1;

    f32x4 acc[4][4] = {};

    const int srow   = l >> 3;                  // 0..7
    const int schunk = ((l & 7) ^ srow) * 16;   // byte offset of swizzled 16B chunk
    const int lm = l & 15;
    const int q  = l >> 4;                      // 0..3
    const int c0 = (q * 2) << 4, c1 = (q * 2 + 1) << 4;

    // ---------------- spline fp8 phase (chunk kz: 64 tiles, counted dbuf) --
    {
        const uint8_t* Ag = A8 + (size_t)(bm * 128 + w * 32 + srow) * K8 + kz * (K8 / SPLITK) + schunk;
        const uint8_t* Bg = W8 + (size_t)(bn * 128 + w * 32 + srow) * K8 + kz * (K8 / SPLITK) + schunk;

        auto stage = [&](int bb) {                  // 8 vmem ops per wave
#pragma unroll
            for (int j = 0; j < 4; ++j) {
                __builtin_amdgcn_global_load_lds(
                    (const uint32_t*)(Ag + (size_t)(j * 8) * K8),
                    (uint32_t*)(&As[bb][(w * 32 + j * 8) * 128]), 16, 0, 0);
                __builtin_amdgcn_global_load_lds(
                    (const uint32_t*)(Bg + (size_t)(j * 8) * K8),
                    (uint32_t*)(&Bs[bb][(w * 32 + j * 8) * 128]), 16, 0, 0);
            }
            Ag += 128; Bg += 128;
        };
        auto compute = [&](int bb) {
            i32x8 bf[4];
#pragma unroll
            for (int j = 0; j < 4; ++j) {
                const int row = wn * 64 + j * 16 + lm;
                const int sw  = (row & 7) << 4;
                const uint8_t* rp = &Bs[bb][row * 128];
                i32x4 lo = *(const i32x4*)(rp + (c0 ^ sw));
                i32x4 hi = *(const i32x4*)(rp + (c1 ^ sw));
                bf[j] = __builtin_shufflevector(lo, hi, 0, 1, 2, 3, 4, 5, 6, 7);
            }
#pragma unroll
            for (int i = 0; i < 4; ++i) {
                const int row = wm * 64 + i * 16 + lm;
                const int sw  = (row & 7) << 4;
                const uint8_t* rp = &As[bb][row * 128];
                i32x4 lo = *(const i32x4*)(rp + (c0 ^ sw));
                i32x4 hi = *(const i32x4*)(rp + (c1 ^ sw));
                i32x8 af = __builtin_shufflevector(lo, hi, 0, 1, 2, 3, 4, 5, 6, 7);
#pragma unroll
                for (int j = 0; j < 4; ++j)
                    acc[i][j] = __builtin_amdgcn_mfma_scale_f32_16x16x128_f8f6f4(
                        af, bf[j], acc[i][j], 0, 0, 0, 0x7f7f7f7f, 0, 0x7f7f7f7f);
            }
        };

        stage(0);                                   // tile 0
        stage(1);                                   // tile 1 (16 ops in flight)
        const int NT = (K8 / SPLITK) / 128;         // 64
        for (int t = 0; t < NT; ++t) {
            // entering iter t: tiles t (buf t&1) and t+1 (buf ~t&1) issued
            if (t < NT - 1) { asm volatile("s_waitcnt vmcnt(8)" ::: "memory"); }
            else            { asm volatile("s_waitcnt vmcnt(0)" ::: "memory"); }
            __builtin_amdgcn_sched_barrier(0);
            __builtin_amdgcn_s_barrier();           // all waves' tile-t slices landed
            compute(t & 1);
            __builtin_amdgcn_s_barrier();           // all waves done reading buf[t&1]
            if (t < NT - 2) stage(t & 1);           // tile t+2 over buf[t&1]
        }
    }

    // undo the WSCALE applied to the fp8 spline weights (in-register)
#pragma unroll
    for (int i = 0; i < 4; ++i)
#pragma unroll
        for (int j = 0; j < 4; ++j)
            acc[i][j] *= (1.0f / WSCALE);

    // ---------------- base bf16 phase: K-slice kz (8 tiles, counted dbuf) --
    {
        const uint8_t* Ag = Ab + (size_t)(bm * 128 + w * 32 + srow) * (KB * 2) + kz * (KB * 2 / SPLITK) + schunk;
        const uint8_t* Bg = Wb + (size_t)(bn * 128 + w * 32 + srow) * (KB * 2) + kz * (KB * 2 / SPLITK) + schunk;

        auto stage = [&](int bb) {
#pragma unroll
            for (int j = 0; j < 4; ++j) {
                __builtin_amdgcn_global_load_lds(
                    (const uint32_t*)(Ag + (size_t)(j * 8) * (KB * 2)),
                    (uint32_t*)(&As[bb][(w * 32 + j * 8) * 128]), 16, 0, 0);
                __builtin_amdgcn_global_load_lds(
                    (const uint32_t*)(Bg + (size_t)(j * 8) * (KB * 2)),
                    (uint32_t*)(&Bs[bb][(w * 32 + j * 8) * 128]), 16, 0, 0);
            }
            Ag += 128; Bg += 128;
        };
        auto compute = [&](int bb) {
#pragma unroll
            for (int h = 0; h < 2; ++h) {
                bf16x8 af[4], bfr[4];
#pragma unroll
                for (int i = 0; i < 4; ++i) {
                    const int row = wm * 64 + i * 16 + lm;
                    af[i] = *(const bf16x8*)(&As[bb][row * 128 + ((((h * 4 + q) ^ (row & 7))) << 4)]);
                }
#pragma unroll
                for (int j = 0; j < 4; ++j) {
                    const int row = wn * 64 + j * 16 + lm;
                    bfr[j] = *(const bf16x8*)(&Bs[bb][row * 128 + ((((h * 4 + q) ^ (row & 7))) << 4)]);
                }
#pragma unroll
                for (int i = 0; i < 4; ++i)
#pragma unroll
                    for (int j = 0; j < 4; ++j)
                        acc[i][j] = __builtin_amdgcn_mfma_f32_16x16x32_bf16(af[i], bfr[j], acc[i][j], 0, 0, 0);
            }
        };

        stage(0);
        stage(1);
        const int NT = (KB * 2 / SPLITK) / 128;     // 8
        for (int t = 0; t < NT; ++t) {
            if (t < NT - 1) { asm volatile("s_waitcnt vmcnt(8)" ::: "memory"); }
            else            { asm volatile("s_waitcnt vmcnt(0)" ::: "memory"); }
            __builtin_amdgcn_sched_barrier(0);
            __builtin_amdgcn_s_barrier();
            compute(t & 1);
            __builtin_amdgcn_s_barrier();
            if (t < NT - 2) stage(t & 1);
        }
    }

    // epilogue: C/D layout col = lane&15, row = (lane>>4)*4 + reg
    const int row0 = bm * 128 + wm * 64 + q * 4;
    const int col0 = bn * 128 + wn * 64 + lm;
#pragma unroll
    for (int i = 0; i < 4; ++i)
#pragma unroll
        for (int j = 0; j < 4; ++j)
#pragma unroll
            for (int r = 0; r < 4; ++r)
                unsafeAtomicAdd(&C[(size_t)(row0 + i * 16 + r) * OUT_DIM + col0 + j * 16],
                                acc[i][j][r]);
}

// ---------------------------------------------------------------------------
extern "C" void kernel_launch(void* const* d_in, const int* in_sizes, int n_in,
                              void* d_out, int out_size, void* d_ws, size_t ws_size,
                              hipStream_t stream) {
    const float* x     = (const float*)d_in[0];   // (B, I)
    const float* sb    = (const float*)d_in[1];   // (O, I)
    const float* ss    = (const float*)d_in[2];   // (O, I)
    const float* coeff = (const float*)d_in[3];   // (2, O, I, G)
    float* out = (float*)d_out;                   // (B, O)

    uint8_t* A8 = (uint8_t*)d_ws;                          // 4096*16384 fp8 = 67.1 MB
    uint8_t* W8 = A8 + (size_t)BATCH * K8;                 // 1024*16384 fp8 = 16.8 MB
    __bf16*  Ab = (__bf16*)(W8 + (size_t)OUT_DIM * K8);    // 4096*1024 bf16 = 8.4 MB
    __bf16*  Wb = Ab + (size_t)BATCH * KB;                 // 1024*1024 bf16 = 2.1 MB

    hipLaunchKernelGGL(prep, dim3(2048), dim3(256), 0, stream,
                       x, sb, ss, coeff, A8, W8, Ab, Wb, out);
    hipLaunchKernelGGL(gemm_all, dim3(OUT_DIM / 128, BATCH / 128, SPLITK), dim3(256), 0, stream,
                       A8, W8, (const uint8_t*)Ab, (const uint8_t*)Wb, out);
}